// Round 2
// baseline (209.234 us; speedup 1.0000x reference)
//
#include <hip/hip_runtime.h>

typedef int v4i __attribute__((ext_vector_type(4)));

#define N_ROWS   262144
#define IN_F     256
#define OUT_F    256
#define N_TILES  (N_ROWS / 16)

// ---------------- prep: weight int32 -> int8, per-channel offset & scale ----
__global__ void qlin_prep(const int* __restrict__ w,      // [256][256] int32
                          const int* __restrict__ bias,   // [256]
                          const float* __restrict__ is,   // [1]
                          const float* __restrict__ wsc,  // [256]
                          const float* __restrict__ os,   // [1]
                          const int* __restrict__ izp,    // [1]
                          signed char* __restrict__ w8,   // [256][256] int8
                          int* __restrict__ off,          // [256]
                          float* __restrict__ scale) {    // [256]
    int o = blockIdx.x;
    int k = threadIdx.x;
    int v = w[o * IN_F + k];
    w8[o * IN_F + k] = (signed char)v;

    __shared__ int red[256];
    red[k] = v;
    __syncthreads();
    for (int s = 128; s > 0; s >>= 1) {
        if (k < s) red[k] += red[k + s];
        __syncthreads();
    }
    if (k == 0) {
        off[o]   = bias[o] - izp[0] * red[0];
        scale[o] = is[0] * wsc[o] / os[0];
    }
}

// ---------------- main GEMM -------------------------------------------------
__device__ inline int pack4(v4i a) {
    return (a.x & 255) | ((a.y & 255) << 8) | ((a.z & 255) << 16) | (a.w << 24);
}

__global__ __launch_bounds__(256) void
qlin_main(const int* __restrict__ x,           // [N][256] int32
          const signed char* __restrict__ w8,  // [256][256] int8 (row o = out ch)
          const int* __restrict__ off,         // [256]
          const float* __restrict__ scale,     // [256]
          const int* __restrict__ ozp,         // [1]
          int* __restrict__ out) {             // [N][256] int32 (int8 values)
    const int wid  = threadIdx.x >> 6;   // wave 0..3 -> column stripe
    const int lane = threadIdx.x & 63;
    const int l15  = lane & 15;
    const int lg   = lane >> 4;          // 0..3
    const int colBase = wid * 64;

    // B fragments: B[k][n] = W[n][k]; lane needs n = colBase+cf*16+l15,
    // k = kc*64 + lg*16 + i (16 contiguous int8 = one dwordx4)
    v4i Bf[4][4];
#pragma unroll
    for (int cf = 0; cf < 4; ++cf) {
        int n = colBase + cf * 16 + l15;
#pragma unroll
        for (int kc = 0; kc < 4; ++kc) {
            Bf[cf][kc] = *(const v4i*)(w8 + n * IN_F + kc * 64 + lg * 16);
        }
    }

    const float ozpf = (float)ozp[0];
    float sc[4];
    int   of[4];
#pragma unroll
    for (int cf = 0; cf < 4; ++cf) {
        int n = colBase + cf * 16 + l15;
        sc[cf] = scale[n];
        of[cf] = off[n];
    }

    for (int t = blockIdx.x; t < N_TILES; t += gridDim.x) {
        const int row0 = t * 16;

        // A fragments: lane holds row l15, k = kc*64 + lg*16 + i (16 int32 -> 16 i8)
        v4i Af[4];
#pragma unroll
        for (int kc = 0; kc < 4; ++kc) {
            const v4i* pv = (const v4i*)(x + (row0 + l15) * IN_F + kc * 64 + lg * 16);
            v4i a0 = pv[0], a1 = pv[1], a2 = pv[2], a3 = pv[3];
            v4i pk;
            pk.x = pack4(a0);
            pk.y = pack4(a1);
            pk.z = pack4(a2);
            pk.w = pack4(a3);
            Af[kc] = pk;
        }

        v4i acc[4];
#pragma unroll
        for (int cf = 0; cf < 4; ++cf) acc[cf] = (v4i){0, 0, 0, 0};

#pragma unroll
        for (int kc = 0; kc < 4; ++kc) {
#pragma unroll
            for (int cf = 0; cf < 4; ++cf) {
                acc[cf] = __builtin_amdgcn_mfma_i32_16x16x64_i8(Af[kc], Bf[cf][kc], acc[cf], 0, 0, 0);
            }
        }

        // Epilogue: C/D layout col = lane&15, row_in_tile = lg*4 + r
#pragma unroll
        for (int cf = 0; cf < 4; ++cf) {
            const int col = colBase + cf * 16 + l15;
#pragma unroll
            for (int r = 0; r < 4; ++r) {
                const int row = row0 + lg * 4 + r;
                float v = (float)(acc[cf][r] + of[cf]) * sc[cf] + ozpf;
                v = rintf(v);
                v = fminf(fmaxf(v, -128.0f), 127.0f);
                out[row * OUT_F + col] = (int)v;
            }
        }
    }
}

extern "C" void kernel_launch(void* const* d_in, const int* in_sizes, int n_in,
                              void* d_out, int out_size, void* d_ws, size_t ws_size,
                              hipStream_t stream) {
    const int*   x   = (const int*)d_in[0];
    const int*   w   = (const int*)d_in[1];
    const int*   b   = (const int*)d_in[2];
    const float* is  = (const float*)d_in[3];
    const float* wsc = (const float*)d_in[4];
    const float* os  = (const float*)d_in[5];
    const int*   izp = (const int*)d_in[6];
    const int*   ozp = (const int*)d_in[7];
    int* out = (int*)d_out;

    signed char* w8    = (signed char*)d_ws;                 // 65536 B
    int*         off   = (int*)((char*)d_ws + 65536);        // 1024 B
    float*       scale = (float*)((char*)d_ws + 66560);      // 1024 B

    qlin_prep<<<256, 256, 0, stream>>>(w, b, is, wsc, os, izp, w8, off, scale);
    qlin_main<<<2048, 256, 0, stream>>>(x, w8, off, scale, ozp, out);
}